// Round 8
// baseline (260.519 us; speedup 1.0000x reference)
//
#include <hip/hip_runtime.h>
#include <cstdint>
#include <cstddef>

typedef __attribute__((ext_vector_type(8))) short bf16x8;
typedef __attribute__((ext_vector_type(4))) unsigned short u16x4;
typedef __attribute__((ext_vector_type(4))) float f32x4;
typedef unsigned short u16;

#define T_TOT 9728
#define DDIM  2048
#define GHN   256
#define NSEQ  8

__device__ __constant__ int OFFS[NSEQ + 1] = {0, 512, 1536, 3072, 5120, 5760, 6656, 7936, 9728};

__device__ __forceinline__ u16 f2bf(float f) {
  union { float f; unsigned u; } v; v.f = f;
  unsigned r = v.u + 0x7FFFu + ((v.u >> 16) & 1u);
  return (u16)(r >> 16);
}
__device__ __forceinline__ float silu_f(float v) {
  return v / (1.0f + __expf(-v));
}

// async global->LDS, 16B per lane, wave-uniform LDS base + lane*16 (m97 pattern)
__device__ __forceinline__ void gload_lds16(const u16* src, u16* dst) {
  __builtin_amdgcn_global_load_lds(
      (__attribute__((address_space(1))) void*)src,
      (__attribute__((address_space(3))) void*)dst,
      16, 0, 0);
}

// ---------------------------------------------------------------------------
// Prep: fp32 [R][C] -> bf16 [C][R]  (transpose + convert), 64x64 tiles
// (validated)
// ---------------------------------------------------------------------------
__global__ __launch_bounds__(256)
void transpose_bf16_k(const float* __restrict__ in, u16* __restrict__ out, int R, int C) {
  __shared__ float tile[64][65];
  const int c0 = blockIdx.x * 64, r0 = blockIdx.y * 64;
  const int tid = threadIdx.x;
  const int lc = tid & 63, lr = tid >> 6;
#pragma unroll
  for (int p = 0; p < 16; ++p) {
    int r = lr + p * 4;
    tile[r][lc] = in[(size_t)(r0 + r) * C + c0 + lc];
  }
  __syncthreads();
#pragma unroll
  for (int p = 0; p < 16; ++p) {
    int c = lr + p * 4;
    out[(size_t)(c0 + c) * R + r0 + lc] = f2bf(tile[lc][c]);
  }
}

// ---------------------------------------------------------------------------
// Kernel A: h = silu(gi @ w1)  (validated; h stored PRE-SWIZZLED:
// element (t,c) at t*256 + ((c>>3)^(t&7))*8 + (c&7))
// ---------------------------------------------------------------------------
__global__ __launch_bounds__(256, 4)
void gemm1_silu(const float* __restrict__ gi, const u16* __restrict__ w1T,
                u16* __restrict__ h) {
  __shared__ u16 A[32][72];
  const int tid = threadIdx.x;
  const int lane = tid & 63, wid = tid >> 6;
  const int l15 = lane & 15, l4 = lane >> 4;
  const int t0 = blockIdx.x * 32;
  const int nb = wid * 64;

  f32x4 acc[2][4] = {};

  for (int k0 = 0; k0 < DDIM; k0 += 64) {
#pragma unroll
    for (int j = 0; j < 2; ++j) {
      int idx = tid + j * 256;
      int m = idx >> 4, f4 = idx & 15;
      f32x4 v = *reinterpret_cast<const f32x4*>(&gi[(size_t)(t0 + m) * DDIM + k0 + f4 * 4]);
      u16x4 b;
      b[0] = f2bf(v[0]); b[1] = f2bf(v[1]); b[2] = f2bf(v[2]); b[3] = f2bf(v[3]);
      *reinterpret_cast<u16x4*>(&A[m][f4 * 4]) = b;
    }
    __syncthreads();
#pragma unroll
    for (int ks = 0; ks < 2; ++ks) {
      bf16x8 af[2], bfr[4];
#pragma unroll
      for (int mi = 0; mi < 2; ++mi)
        af[mi] = *reinterpret_cast<const bf16x8*>(&A[mi * 16 + l15][ks * 32 + 8 * l4]);
#pragma unroll
      for (int ni = 0; ni < 4; ++ni)
        bfr[ni] = *reinterpret_cast<const bf16x8*>(
            &w1T[(size_t)(nb + ni * 16 + l15) * DDIM + k0 + ks * 32 + 8 * l4]);
#pragma unroll
      for (int mi = 0; mi < 2; ++mi)
#pragma unroll
        for (int ni = 0; ni < 4; ++ni)
          acc[mi][ni] = __builtin_amdgcn_mfma_f32_16x16x32_bf16(af[mi], bfr[ni], acc[mi][ni], 0, 0, 0);
    }
    __syncthreads();
  }

#pragma unroll
  for (int mi = 0; mi < 2; ++mi)
#pragma unroll
    for (int ni = 0; ni < 4; ++ni)
#pragma unroll
      for (int r = 0; r < 4; ++r) {
        float v = silu_f(acc[mi][ni][r]);
        int token = t0 + mi * 16 + l4 * 4 + r;
        int c = nb + ni * 16 + l15;
        int pos = ((((c >> 3) ^ (token & 7)) << 3) | (c & 7));
        h[(size_t)token * GHN + pos] = f2bf(v);
      }
}

// ---------------------------------------------------------------------------
// Kernel B: fused kern = h@w2+b2 -> 4-tap conv -> silu -> out.
// grid (38 tg, 64 col-tiles of 128); 256 thr / 4 waves; wave owns 32 cols (8 d).
// PERMUTED column ownership: lane l15's B-frags load orig cols
//   colwave + 4*(l15>>1) + 2*(l15&1) + ni   (ni = 0,1)
// so channel d = dwave + (l15>>1) has taps {k0,k0+1} lane-local and {k0^2,..}
// in the xor-1 partner lane -> conv = 8 FMA + 4 shfl_xor, NO LDS exchange.
// Staging via global_load_lds issued post-GEMM (overlaps epilogue).
// ---------------------------------------------------------------------------
__global__ __launch_bounds__(256, 4)
void gemm2_conv(const u16* __restrict__ h, const u16* __restrict__ w2T,
                const float* __restrict__ b2, const float* __restrict__ x,
                const float* __restrict__ cs, float* __restrict__ out) {
  __shared__ u16 H[64 * 256];  // 32KB single buffer
  const int tid = threadIdx.x;
  const int lane = tid & 63, wid = tid >> 6;
  const int l15 = lane & 15, l4 = lane >> 4;
  const int colwave = blockIdx.y * 128 + wid * 32;
  const int tg = blockIdx.x;

  // permuted original-column base for this lane (ni adds 0/1)
  const int ocol = colwave + 4 * (l15 >> 1) + 2 * (l15 & 1);

  // w2 fragments register-resident, permuted rows (loaded once)
  bf16x8 bw[8][2];
#pragma unroll
  for (int ks = 0; ks < 8; ++ks)
#pragma unroll
    for (int ni = 0; ni < 2; ++ni)
      bw[ks][ni] = *reinterpret_cast<const bf16x8*>(
          w2T + (size_t)(ocol + ni) * GHN + ks * 32 + l4 * 8);

  float b2v[2];
#pragma unroll
  for (int ni = 0; ni < 2; ++ni) b2v[ni] = b2[ocol + ni];

  const int d = (colwave >> 2) + (l15 >> 1);  // this lane's conv channel
  const int k0 = 2 * (l15 & 1);               // first tap held by this lane
  const int par = lane & 1;                   // parity: stores r in {2par, 2par+1}

  // prologue: stage chunk 0 (linear dest: h is pre-swizzled)
  {
    const u16* hb = h + (size_t)(tg * 4) * 64 * GHN;
#pragma unroll
    for (int p = 0; p < 8; ++p)
      gload_lds16(hb + (size_t)(p * 256 + tid) * 8, &H[(p * 256 + tid) * 8]);
  }
  __syncthreads();  // vmcnt drained before barrier -> chunk 0 visible

  for (int it = 0; it < 4; ++it) {
    const int t0 = (tg * 4 + it) * 64;

    // ---- GEMM: 8 ks x (4 A-frag ds_read + 8 MFMA), B in registers ----
    f32x4 acc[4][2] = {};
#pragma unroll
    for (int ks = 0; ks < 8; ++ks) {
#pragma unroll
      for (int mi = 0; mi < 4; ++mi) {
        int m = mi * 16 + l15;
        int g = ks * 4 + l4;
        bf16x8 af = *reinterpret_cast<const bf16x8*>(&H[m * 256 + ((g ^ (m & 7)) << 3)]);
#pragma unroll
        for (int ni = 0; ni < 2; ++ni)
          acc[mi][ni] = __builtin_amdgcn_mfma_f32_16x16x32_bf16(af, bw[ks][ni], acc[mi][ni], 0, 0, 0);
      }
    }

    __syncthreads();  // barrier A: all waves' H reads complete

    // issue next chunk's staging now; flight hides under the conv epilogue
    if (it < 3) {
      const u16* hb = h + (size_t)(t0 + 64) * GHN;
#pragma unroll
      for (int p = 0; p < 8; ++p)
        gload_lds16(hb + (size_t)(p * 256 + tid) * 8, &H[(p * 256 + tid) * 8]);
    }

    // ---- conv epilogue: lane-local taps + one shfl_xor, no LDS ----
    int iseq = 0;
    while (OFFS[iseq + 1] <= t0) ++iseq;
    const int seq_start = OFFS[iseq];

#pragma unroll
    for (int mi = 0; mi < 4; ++mi) {
      const int base = t0 + mi * 16 + l4 * 4;
      // x window: xw[j] = x(base + j + k0 - 3, d), j=0..4 covers r+ni
      float xw[5];
#pragma unroll
      for (int j = 0; j < 5; ++j) {
        int src = base + j + k0 - 3;
        xw[j] = (src >= seq_start)
                    ? x[(size_t)src * DDIM + d]
                    : cs[((size_t)iseq * DDIM + d) * 3 + (src - seq_start + 3)];
      }
#pragma unroll
      for (int r = 0; r < 4; ++r) {
        float partial = (acc[mi][0][r] + b2v[0]) * xw[r] +
                        (acc[mi][1][r] + b2v[1]) * xw[r + 1];
        float tot = partial + __shfl_xor(partial, 1);
        if ((r >> 1) == par)  // even lanes store r=0,1; odd lanes r=2,3
          out[(size_t)(base + r) * DDIM + d] = silu_f(tot);
      }
    }

    __syncthreads();  // barrier B: vmcnt drain publishes chunk it+1
  }
}

// ---------------------------------------------------------------------------
// Kernel C: new_conv_state[i][d][m] = x[offs[i+1]-3+m][d]
// ---------------------------------------------------------------------------
__global__ __launch_bounds__(256)
void tail_state(const float* __restrict__ x, float* __restrict__ out2) {
  int idx = blockIdx.x * 256 + threadIdx.x;
  int i = idx / (DDIM * 3);
  int rem = idx - i * (DDIM * 3);
  int d = rem / 3, m = rem - d * 3;
  int token = OFFS[i + 1] - 3 + m;
  out2[idx] = x[(size_t)token * DDIM + d];
}

// ---------------------------------------------------------------------------
extern "C" void kernel_launch(void* const* d_in, const int* in_sizes, int n_in,
                              void* d_out, int out_size, void* d_ws, size_t ws_size,
                              hipStream_t stream) {
  (void)in_sizes; (void)n_in; (void)out_size; (void)ws_size;
  const float* x  = (const float*)d_in[0];
  const float* cs = (const float*)d_in[1];
  const float* gi = (const float*)d_in[2];
  const float* w1 = (const float*)d_in[4];
  const float* w2 = (const float*)d_in[5];
  const float* b2 = (const float*)d_in[6];
  float* out = (float*)d_out;

  char* ws = (char*)d_ws;
  u16* w2T = (u16*)ws;                        // [8192][256] bf16 : 4,194,304 B
  u16* w1T = (u16*)(ws + 4194304);            // [256][2048] bf16 : 1,048,576 B
  u16* h   = (u16*)(ws + 4194304 + 1048576);  // [9728][256] bf16 swizzled : 4,980,736 B

  transpose_bf16_k<<<dim3(8192 / 64, 256 / 64), 256, 0, stream>>>(w2, w2T, GHN, DDIM * 4);
  transpose_bf16_k<<<dim3(256 / 64, 2048 / 64), 256, 0, stream>>>(w1, w1T, DDIM, GHN);
  gemm1_silu<<<T_TOT / 32, 256, 0, stream>>>(gi, w1T, h);
  // each block: 4 waves x 32 cols = 128 of the D*K = 8192 kern columns -> 64 y-blocks
  gemm2_conv<<<dim3(T_TOT / 256, (DDIM * 4) / 128), 256, 0, stream>>>(h, w2T, b2, x, cs, out);
  tail_state<<<(NSEQ * DDIM * 3) / 256, 256, 0, stream>>>(x, out + (size_t)T_TOT * DDIM);
}

// Round 9
// 193.292 us; speedup vs baseline: 1.3478x; 1.3478x over previous
//
#include <hip/hip_runtime.h>
#include <cstdint>
#include <cstddef>

typedef __attribute__((ext_vector_type(8))) short bf16x8;
typedef __attribute__((ext_vector_type(4))) unsigned short u16x4;
typedef __attribute__((ext_vector_type(4))) unsigned u32x4;
typedef __attribute__((ext_vector_type(4))) float f32x4;
typedef unsigned short u16;

#define T_TOT 9728
#define DDIM  2048
#define GHN   256
#define NSEQ  8

__device__ __constant__ int OFFS[NSEQ + 1] = {0, 512, 1536, 3072, 5120, 5760, 6656, 7936, 9728};

__device__ __forceinline__ u16 f2bf(float f) {
  union { float f; unsigned u; } v; v.f = f;
  unsigned r = v.u + 0x7FFFu + ((v.u >> 16) & 1u);
  return (u16)(r >> 16);
}
__device__ __forceinline__ float silu_f(float v) {
  return v / (1.0f + __expf(-v));
}

// Pin a 128-bit value into VGPRs: volatile asm redefines it, so the compiler
// cannot rematerialize the originating load inside later loops.
__device__ __forceinline__ void pin_reg(bf16x8& v) {
  u32x4& u = reinterpret_cast<u32x4&>(v);
  asm volatile("" : "+v"(u));
}

// async global->LDS, 16B per lane, wave-uniform LDS base + lane*16 (m97 pattern)
__device__ __forceinline__ void gload_lds16(const u16* src, u16* dst) {
  __builtin_amdgcn_global_load_lds(
      (__attribute__((address_space(1))) void*)src,
      (__attribute__((address_space(3))) void*)dst,
      16, 0, 0);
}

// ---------------------------------------------------------------------------
// Prep: fp32 [R][C] -> bf16 [C][R]  (transpose + convert), 64x64 tiles
// ---------------------------------------------------------------------------
__global__ __launch_bounds__(256)
void transpose_bf16_k(const float* __restrict__ in, u16* __restrict__ out, int R, int C) {
  __shared__ float tile[64][65];
  const int c0 = blockIdx.x * 64, r0 = blockIdx.y * 64;
  const int tid = threadIdx.x;
  const int lc = tid & 63, lr = tid >> 6;
#pragma unroll
  for (int p = 0; p < 16; ++p) {
    int r = lr + p * 4;
    tile[r][lc] = in[(size_t)(r0 + r) * C + c0 + lc];
  }
  __syncthreads();
#pragma unroll
  for (int p = 0; p < 16; ++p) {
    int c = lr + p * 4;
    out[(size_t)(c0 + c) * R + r0 + lc] = f2bf(tile[lc][c]);
  }
}

// ---------------------------------------------------------------------------
// Kernel A: h = silu(gi @ w1)  (validated; h stored PRE-SWIZZLED:
// element (t,c) at t*256 + ((c>>3)^(t&7))*8 + (c&7))
// ---------------------------------------------------------------------------
__global__ __launch_bounds__(256, 4)
void gemm1_silu(const float* __restrict__ gi, const u16* __restrict__ w1T,
                u16* __restrict__ h) {
  __shared__ u16 A[32][72];
  const int tid = threadIdx.x;
  const int lane = tid & 63, wid = tid >> 6;
  const int l15 = lane & 15, l4 = lane >> 4;
  const int t0 = blockIdx.x * 32;
  const int nb = wid * 64;

  f32x4 acc[2][4] = {};

  for (int k0 = 0; k0 < DDIM; k0 += 64) {
#pragma unroll
    for (int j = 0; j < 2; ++j) {
      int idx = tid + j * 256;
      int m = idx >> 4, f4 = idx & 15;
      f32x4 v = *reinterpret_cast<const f32x4*>(&gi[(size_t)(t0 + m) * DDIM + k0 + f4 * 4]);
      u16x4 b;
      b[0] = f2bf(v[0]); b[1] = f2bf(v[1]); b[2] = f2bf(v[2]); b[3] = f2bf(v[3]);
      *reinterpret_cast<u16x4*>(&A[m][f4 * 4]) = b;
    }
    __syncthreads();
#pragma unroll
    for (int ks = 0; ks < 2; ++ks) {
      bf16x8 af[2], bfr[4];
#pragma unroll
      for (int mi = 0; mi < 2; ++mi)
        af[mi] = *reinterpret_cast<const bf16x8*>(&A[mi * 16 + l15][ks * 32 + 8 * l4]);
#pragma unroll
      for (int ni = 0; ni < 4; ++ni)
        bfr[ni] = *reinterpret_cast<const bf16x8*>(
            &w1T[(size_t)(nb + ni * 16 + l15) * DDIM + k0 + ks * 32 + 8 * l4]);
#pragma unroll
      for (int mi = 0; mi < 2; ++mi)
#pragma unroll
        for (int ni = 0; ni < 4; ++ni)
          acc[mi][ni] = __builtin_amdgcn_mfma_f32_16x16x32_bf16(af[mi], bfr[ni], acc[mi][ni], 0, 0, 0);
    }
    __syncthreads();
  }

#pragma unroll
  for (int mi = 0; mi < 2; ++mi)
#pragma unroll
    for (int ni = 0; ni < 4; ++ni)
#pragma unroll
      for (int r = 0; r < 4; ++r) {
        float v = silu_f(acc[mi][ni][r]);
        int token = t0 + mi * 16 + l4 * 4 + r;
        int c = nb + ni * 16 + l15;
        int pos = ((((c >> 3) ^ (token & 7)) << 3) | (c & 7));
        h[(size_t)token * GHN + pos] = f2bf(v);
      }
}

// ---------------------------------------------------------------------------
// Kernel B: fused kern = h@w2+b2 -> 4-tap conv -> silu -> out.
// grid (38 tg, 64 col-tiles of 128); 256 thr / 4 waves; wave owns 32 cols (8 d).
// bw PINNED register-resident (asm barrier prevents rematerialization).
// Permuted col ownership (validated r8): lane l15 loads orig cols
//   colwave + 4*(l15>>1) + 2*(l15&1) + ni  -> conv = FMA + shfl_xor(1), no LDS.
// Out-staging in LDS -> dense 128B-per-token stores (one wave per line).
// ---------------------------------------------------------------------------
__global__ __launch_bounds__(256, 3)
void gemm2_conv(const u16* __restrict__ h, const u16* __restrict__ w2T,
                const float* __restrict__ b2, const float* __restrict__ x,
                const float* __restrict__ cs, float* __restrict__ out) {
  __shared__ u16 H[64 * 256];      // 32KB single buffer
  __shared__ float Ot[64 * 33];    // 8.25KB out-staging, pad-33
  const int tid = threadIdx.x;
  const int lane = tid & 63, wid = tid >> 6;
  const int l15 = lane & 15, l4 = lane >> 4;
  const int colwave = blockIdx.y * 128 + wid * 32;
  const int d0 = blockIdx.y * 32;      // block's 32-channel base
  const int tg = blockIdx.x;

  // permuted original-column base for this lane (ni adds 0/1)
  const int ocol = colwave + 4 * (l15 >> 1) + 2 * (l15 & 1);

  // w2 fragments: load once, then PIN in VGPRs
  bf16x8 bw[8][2];
#pragma unroll
  for (int ks = 0; ks < 8; ++ks)
#pragma unroll
    for (int ni = 0; ni < 2; ++ni)
      bw[ks][ni] = *reinterpret_cast<const bf16x8*>(
          w2T + (size_t)(ocol + ni) * GHN + ks * 32 + l4 * 8);
#pragma unroll
  for (int ks = 0; ks < 8; ++ks)
#pragma unroll
    for (int ni = 0; ni < 2; ++ni)
      pin_reg(bw[ks][ni]);

  float b2v[2];
#pragma unroll
  for (int ni = 0; ni < 2; ++ni) b2v[ni] = b2[ocol + ni];

  const int d = (colwave >> 2) + (l15 >> 1);  // this lane's conv channel
  const int dloc = wid * 8 + (l15 >> 1);      // channel within block (0..31)
  const int k0 = 2 * (l15 & 1);               // first tap held by this lane
  const int par = lane & 1;

  // prologue: stage chunk 0 (linear dest: h is pre-swizzled)
  {
    const u16* hb = h + (size_t)(tg * 4) * 64 * GHN;
#pragma unroll
    for (int p = 0; p < 8; ++p)
      gload_lds16(hb + (size_t)(p * 256 + tid) * 8, &H[(p * 256 + tid) * 8]);
  }
  __syncthreads();

  for (int it = 0; it < 4; ++it) {
    const int t0 = (tg * 4 + it) * 64;

    // ---- GEMM: 8 ks x (4 A-frag ds_read + 8 MFMA), B pinned in regs ----
    f32x4 acc[4][2] = {};
#pragma unroll
    for (int ks = 0; ks < 8; ++ks) {
#pragma unroll
      for (int mi = 0; mi < 4; ++mi) {
        int m = mi * 16 + l15;
        int g = ks * 4 + l4;
        bf16x8 af = *reinterpret_cast<const bf16x8*>(&H[m * 256 + ((g ^ (m & 7)) << 3)]);
#pragma unroll
        for (int ni = 0; ni < 2; ++ni)
          acc[mi][ni] = __builtin_amdgcn_mfma_f32_16x16x32_bf16(af, bw[ks][ni], acc[mi][ni], 0, 0, 0);
      }
    }

    __syncthreads();  // barrier A: all H reads complete

    // issue next chunk's staging; flight hides under conv + out-store
    if (it < 3) {
      const u16* hb = h + (size_t)(t0 + 64) * GHN;
#pragma unroll
      for (int p = 0; p < 8; ++p)
        gload_lds16(hb + (size_t)(p * 256 + tid) * 8, &H[(p * 256 + tid) * 8]);
    }

    // ---- conv epilogue: lane-local taps + shfl_xor, results -> Ot ----
    int iseq = 0;
    while (OFFS[iseq + 1] <= t0) ++iseq;
    const int seq_start = OFFS[iseq];

#pragma unroll
    for (int mi = 0; mi < 4; ++mi) {
      const int base = t0 + mi * 16 + l4 * 4;
      float xw[5];
#pragma unroll
      for (int j = 0; j < 5; ++j) {
        int src = base + j + k0 - 3;
        xw[j] = (src >= seq_start)
                    ? x[(size_t)src * DDIM + d]
                    : cs[((size_t)iseq * DDIM + d) * 3 + (src - seq_start + 3)];
      }
#pragma unroll
      for (int r = 0; r < 4; ++r) {
        float partial = (acc[mi][0][r] + b2v[0]) * xw[r] +
                        (acc[mi][1][r] + b2v[1]) * xw[r + 1];
        float tot = partial + __shfl_xor(partial, 1);
        if ((r >> 1) == par)
          Ot[(mi * 16 + l4 * 4 + r) * 33 + dloc] = silu_f(tot);
      }
    }

    __syncthreads();  // barrier C: Ot complete (also covers H-write hazard)

    // ---- coalesced out-store: 4 threads = one dense 128B token row ----
    {
      const int trow = tid >> 2, tq = tid & 3;
      f32x4 o0 = *reinterpret_cast<const f32x4*>(&Ot[trow * 33 + tq * 8]);
      f32x4 o1 = *reinterpret_cast<const f32x4*>(&Ot[trow * 33 + tq * 8 + 4]);
      float* op = out + (size_t)(t0 + trow) * DDIM + d0 + tq * 8;
      *reinterpret_cast<f32x4*>(op) = o0;
      *reinterpret_cast<f32x4*>(op + 4) = o1;
    }

    __syncthreads();  // barrier B: vmcnt drain publishes chunk it+1 into H
  }
}

// ---------------------------------------------------------------------------
// Kernel C: new_conv_state[i][d][m] = x[offs[i+1]-3+m][d]
// ---------------------------------------------------------------------------
__global__ __launch_bounds__(256)
void tail_state(const float* __restrict__ x, float* __restrict__ out2) {
  int idx = blockIdx.x * 256 + threadIdx.x;
  int i = idx / (DDIM * 3);
  int rem = idx - i * (DDIM * 3);
  int d = rem / 3, m = rem - d * 3;
  int token = OFFS[i + 1] - 3 + m;
  out2[idx] = x[(size_t)token * DDIM + d];
}

// ---------------------------------------------------------------------------
extern "C" void kernel_launch(void* const* d_in, const int* in_sizes, int n_in,
                              void* d_out, int out_size, void* d_ws, size_t ws_size,
                              hipStream_t stream) {
  (void)in_sizes; (void)n_in; (void)out_size; (void)ws_size;
  const float* x  = (const float*)d_in[0];
  const float* cs = (const float*)d_in[1];
  const float* gi = (const float*)d_in[2];
  const float* w1 = (const float*)d_in[4];
  const float* w2 = (const float*)d_in[5];
  const float* b2 = (const float*)d_in[6];
  float* out = (float*)d_out;

  char* ws = (char*)d_ws;
  u16* w2T = (u16*)ws;                        // [8192][256] bf16 : 4,194,304 B
  u16* w1T = (u16*)(ws + 4194304);            // [256][2048] bf16 : 1,048,576 B
  u16* h   = (u16*)(ws + 4194304 + 1048576);  // [9728][256] bf16 swizzled : 4,980,736 B

  transpose_bf16_k<<<dim3(8192 / 64, 256 / 64), 256, 0, stream>>>(w2, w2T, GHN, DDIM * 4);
  transpose_bf16_k<<<dim3(256 / 64, 2048 / 64), 256, 0, stream>>>(w1, w1T, DDIM, GHN);
  gemm1_silu<<<T_TOT / 32, 256, 0, stream>>>(gi, w1T, h);
  // each block: 4 waves x 32 cols = 128 of the D*K = 8192 kern columns -> 64 y-blocks
  gemm2_conv<<<dim3(T_TOT / 256, (DDIM * 4) / 128), 256, 0, stream>>>(h, w2T, b2, x, cs, out);
  tail_state<<<(NSEQ * DDIM * 3) / 256, 256, 0, stream>>>(x, out + (size_t)T_TOT * DDIM);
}